// Round 22
// baseline (241.223 us; speedup 1.0000x reference)
//
#include <hip/hip_runtime.h>
#include <cstdint>

typedef unsigned short u16;
typedef uint32_t u32;
typedef __attribute__((ext_vector_type(8))) short bf16x8;
typedef __attribute__((ext_vector_type(4))) short bf16x4;
typedef __attribute__((ext_vector_type(4))) float f32x4;

#define NB 4
#define NT 2048
#define NC 1024
#define NH 16
#define ND 64
#define NM (NB*NT)      // 8192
#define N3C (3*NC)      // 3072
#define NQT (NT/64)     // 32 q-tiles per (b,h)

// Q scale: 1/sqrt(64) * log2(e)  (softmax runs in log2 domain -> exp2)
#define QSCALE 0.18033688011112042f

static __device__ __forceinline__ u16 f2bf(float f){
  union { float f; uint32_t u; } v; v.f = f;
  return (u16)((v.u + 0x7fffu + ((v.u >> 16) & 1u)) >> 16);
}

// async 16B global->LDS (LDS dest is wave-uniform base + lane*16)
static __device__ __forceinline__ void gld_lds16(void* lds, const void* g){
  auto lp = reinterpret_cast<__attribute__((address_space(3))) uint32_t*>(
      reinterpret_cast<uintptr_t>(lds));
  auto gp = reinterpret_cast<__attribute__((address_space(1))) uint32_t*>(
      reinterpret_cast<uintptr_t>(g));
  __builtin_amdgcn_global_load_lds(gp, lp, 16, 0, 0);
}

static __device__ __forceinline__ f32x4 mfma16(bf16x4 a, bf16x4 b, f32x4 c){
#if __has_builtin(__builtin_amdgcn_mfma_f32_16x16x16bf16_1k)
  return __builtin_amdgcn_mfma_f32_16x16x16bf16_1k(a, b, c, 0, 0, 0);
#else
  asm("v_mfma_f32_16x16x16_bf16 %0, %1, %2, %0" : "+v"(c) : "v"(a), "v"(b));
  return c;
#endif
}

// ---------------- tiled transpose + cast: in[R][Cc] fp32 -> out[Cc][R] bf16 ----------------
__global__ __launch_bounds__(256) void k_transpose_cast(const float* __restrict__ in,
                                                        u16* __restrict__ out,
                                                        int R, int Cc){
  __shared__ float tile[32][33];
  const int bx = blockIdx.x * 32, by = blockIdx.y * 32;
  const int tx = threadIdx.x, ty = threadIdx.y;
#pragma unroll
  for (int i = 0; i < 32; i += 8)
    tile[ty + i][tx] = in[(size_t)(by + ty + i) * Cc + bx + tx];
  __syncthreads();
#pragma unroll
  for (int i = 0; i < 32; i += 8)
    out[(size_t)(bx + ty + i) * R + by + tx] = f2bf(tile[tx][ty + i]);
}

// ---------------- GEMM main loop (proj): C[128x128] tile, BK=32, bf16 A ----------------
static __device__ __forceinline__ void gemm_mainloop(
    const u16* __restrict__ A, const u16* __restrict__ Bt, int K,
    int m0, int n0, u16* As, u16* Bs, f32x4 acc[4][4])
{
  const int tid = threadIdx.x;
  const int wave = tid >> 6, lane = tid & 63;
  const int wm = wave >> 1, wn = wave & 1;
  const int o0 = tid * 8, o1 = o0 + 2048;           // elem offsets in the 128x32 tile
  const u16* Ag0 = A  + (size_t)(m0 + (o0 >> 5)) * K + (o0 & 31);
  const u16* Ag1 = A  + (size_t)(m0 + (o1 >> 5)) * K + (o1 & 31);
  const u16* Bg0 = Bt + (size_t)(n0 + (o0 >> 5)) * K + (o0 & 31);
  const u16* Bg1 = Bt + (size_t)(n0 + (o1 >> 5)) * K + (o1 & 31);
  u16* AsW = As + wave * 512;   // wave-uniform LDS base (1024 B per wave)
  u16* BsW = Bs + wave * 512;
  const int kb = (lane >> 4) * 8, rl = lane & 15;

  for (int kt = 0; kt < K; kt += 32){
    gld_lds16(AsW,        Ag0 + kt);
    gld_lds16(AsW + 2048, Ag1 + kt);
    gld_lds16(BsW,        Bg0 + kt);
    gld_lds16(BsW + 2048, Bg1 + kt);
    __syncthreads();
    bf16x8 af[4], bfr[4];
#pragma unroll
    for (int i = 0; i < 4; i++){
      af[i]  = *reinterpret_cast<const bf16x8*>(&As[(wm * 64 + i * 16 + rl) * 32 + kb]);
      bfr[i] = *reinterpret_cast<const bf16x8*>(&Bs[(wn * 64 + i * 16 + rl) * 32 + kb]);
    }
#pragma unroll
    for (int i = 0; i < 4; i++)
#pragma unroll
      for (int j = 0; j < 4; j++)
        acc[i][j] = __builtin_amdgcn_mfma_f32_16x16x32_bf16(af[i], bfr[j], acc[i][j], 0, 0, 0);
    __syncthreads();
  }
}

// ---------------- GEMM main loop (qkv): fp32 A reg-staged with fused cast ----------------
// A-tile (128x32 fp32): 4 chunks, each thread loads float4, converts, ds_write_b64.
// Replaces the separate k_cast kernel entirely.
static __device__ __forceinline__ void gemm_mainloop_xf32(
    const float* __restrict__ X, const u16* __restrict__ Bt, int K,
    int m0, int n0, u16* As, u16* Bs, f32x4 acc[4][4])
{
  const int tid = threadIdx.x;
  const int wave = tid >> 6, lane = tid & 63;
  const int wm = wave >> 1, wn = wave & 1;
  const int o0 = tid * 8, o1 = o0 + 2048;
  const u16* Bg0 = Bt + (size_t)(n0 + (o0 >> 5)) * K + (o0 & 31);
  const u16* Bg1 = Bt + (size_t)(n0 + (o1 >> 5)) * K + (o1 & 31);
  u16* BsW = Bs + wave * 512;
  const int kb = (lane >> 4) * 8, rl = lane & 15;

  for (int kt = 0; kt < K; kt += 32){
    gld_lds16(BsW,        Bg0 + kt);
    gld_lds16(BsW + 2048, Bg1 + kt);
#pragma unroll
    for (int c = 0; c < 4; c++){
      const int o = c * 1024 + tid * 4;    // row = o>>5, col = o&31 (col multiple of 4)
      const int row = o >> 5, col = o & 31;
      const float4 xv = *reinterpret_cast<const float4*>(
          &X[(size_t)(m0 + row) * K + kt + col]);
      union { u16 s[4]; uint64_t u; } p;
      p.s[0] = f2bf(xv.x); p.s[1] = f2bf(xv.y);
      p.s[2] = f2bf(xv.z); p.s[3] = f2bf(xv.w);
      *reinterpret_cast<uint64_t*>(&As[row * 32 + col]) = p.u;
    }
    __syncthreads();
    bf16x8 af[4], bfr[4];
#pragma unroll
    for (int i = 0; i < 4; i++){
      af[i]  = *reinterpret_cast<const bf16x8*>(&As[(wm * 64 + i * 16 + rl) * 32 + kb]);
      bfr[i] = *reinterpret_cast<const bf16x8*>(&Bs[(wn * 64 + i * 16 + rl) * 32 + kb]);
    }
#pragma unroll
    for (int i = 0; i < 4; i++)
#pragma unroll
      for (int j = 0; j < 4; j++)
        acc[i][j] = __builtin_amdgcn_mfma_f32_16x16x32_bf16(af[i], bfr[j], acc[i][j], 0, 0, 0);
    __syncthreads();
  }
}

// ---------------- GEMM 1: x(f32) @ w_qkv + b_qkv -> Q (scaled), K (swizzled), V (transposed+swizzled)
// 1D grid 1536, XCD swizzle (T1): each XCD gets 8 contiguous M-row panels (A L2-resident).
// Q: [b,h,t,d] standard, values * QSCALE
// K: per (b,h): tile kt (4096 elems): (t&63)*64 + (d ^ ((t&7)<<3))
// V: per (b,h): tile kt (4096 elems): d*64 + (((t>>2)&15 ^ (d&7))<<2) + (t&3)   [transposed]
__global__ __launch_bounds__(256) void k_gemm_qkv(
    const float* __restrict__ X, const u16* __restrict__ Bt,
    const float* __restrict__ bias,
    u16* __restrict__ qo, u16* __restrict__ ko, u16* __restrict__ vo)
{
  __shared__ u16 As[128 * 32], Bs[128 * 32];
  f32x4 acc[4][4] = {};
  const int bid = blockIdx.x;
  const int swz = (bid & 7) * 192 + (bid >> 3);   // 1536/8 = 192 per XCD, m-major chunks
  const int m0 = (swz / 24) * 128, n0 = (swz % 24) * 128;
  gemm_mainloop_xf32(X, Bt, NC, m0, n0, As, Bs, acc);

  const int tid = threadIdx.x;
  const int wave = tid >> 6, lane = tid & 63;
  const int wm = wave >> 1, wn = wave & 1;
  const int rl = lane & 15, rg = lane >> 4;
  const int which = n0 >> 10;   // uniform per block: 0=Q 1=K 2=V
  if (which == 2){
    // V: pack 4 consecutive t (r=0..3, t&3=r) into one 8B store
#pragma unroll
    for (int j = 0; j < 4; j++){
      const int n = n0 + wn * 64 + j * 16 + rl;
      const int cc = n & 1023;
      const int h = cc >> 6, d = cc & 63;
      const float bb = bias[n];
#pragma unroll
      for (int i = 0; i < 4; i++){
        const int mb = m0 + wm * 64 + i * 16 + rg * 4;
        const int b = mb >> 11, t0 = mb & 2047;
        const size_t bhb = ((size_t)(b * NH + h)) * NT * ND;
        union { u16 s[4]; uint64_t u; } pk4;
#pragma unroll
        for (int r = 0; r < 4; r++) pk4.s[r] = f2bf(acc[i][j][r] + bb);
        *reinterpret_cast<uint64_t*>(
          &vo[bhb + (size_t)(t0 >> 6) * 4096 + d * 64 + ((((t0 >> 2) & 15) ^ (d & 7)) << 2)]) = pk4.u;
      }
    }
  } else {
#pragma unroll
    for (int j = 0; j < 4; j++){
      const int n = n0 + wn * 64 + j * 16 + rl;
      const int cc = n & 1023;
      const int h = cc >> 6, d = cc & 63;
      const float bb = bias[n];
#pragma unroll
      for (int i = 0; i < 4; i++){
#pragma unroll
        for (int r = 0; r < 4; r++){
          const int m = m0 + wm * 64 + i * 16 + rg * 4 + r;
          const int b = m >> 11, t = m & 2047;
          const size_t bhb = ((size_t)(b * NH + h)) * NT * ND;
          const float val = acc[i][j][r] + bb;
          if (which == 0){
            qo[bhb + (size_t)t * ND + d] = f2bf(val * QSCALE);
          } else {
            ko[bhb + (size_t)(t >> 6) * 4096 + (t & 63) * 64 + (d ^ ((t & 7) << 3))] = f2bf(val);
          }
        }
      }
    }
  }
}

// ---------------- GEMM 2: attn_out @ w_proj + b_proj -> fp32 out ----------------
// 1D grid 512, XCD swizzle: each XCD gets an 8x8 tile chunk (A 2MB + B 2MB ~ L2).
__global__ __launch_bounds__(256) void k_gemm_proj(
    const u16* __restrict__ A, const u16* __restrict__ Bt,
    const float* __restrict__ bias, float* __restrict__ out)
{
  __shared__ u16 As[128 * 32], Bs[128 * 32];
  f32x4 acc[4][4] = {};
  const int bid = blockIdx.x;
  const int swz = (bid & 7) * 64 + (bid >> 3);    // 512/8 = 64 per XCD
  const int m0 = (swz >> 3) * 128, n0 = (swz & 7) * 128;
  gemm_mainloop(A, Bt, NC, m0, n0, As, Bs, acc);

  const int tid = threadIdx.x;
  const int wave = tid >> 6, lane = tid & 63;
  const int wm = wave >> 1, wn = wave & 1;
  const int rl = lane & 15, rg = lane >> 4;
#pragma unroll
  for (int i = 0; i < 4; i++){
#pragma unroll
    for (int r = 0; r < 4; r++){
      const int m = m0 + wm * 64 + i * 16 + rg * 4 + r;
#pragma unroll
      for (int j = 0; j < 4; j++){
        const int n = n0 + wn * 64 + j * 16 + rl;
        out[(size_t)m * NC + n] = acc[i][j][r] + bias[n];
      }
    }
  }
}

// ---------------- flash helpers ----------------
// S^T = K Q^T : s[nf] holds S^T[k = nf*16 + g*4 + r][q = cl]
static __device__ __forceinline__ void qkt(const u16* __restrict__ KsC,
                                           bf16x8 qf0, bf16x8 qf1,
                                           int cl, int g, f32x4 s[4])
{
  __builtin_amdgcn_s_setprio(1);
#pragma unroll
  for (int nf = 0; nf < 4; nf++){
    const int kj = nf * 16 + cl;
    const u16* krow = &KsC[kj * 64];
    const bf16x8 kf0 = *reinterpret_cast<const bf16x8*>(&krow[((0 + g) ^ (kj & 7)) * 8]);
    const bf16x8 kf1 = *reinterpret_cast<const bf16x8*>(&krow[((4 + g) ^ (kj & 7)) * 8]);
    f32x4 a = {};
    a = __builtin_amdgcn_mfma_f32_16x16x32_bf16(kf0, qf0, a, 0, 0, 0);
    a = __builtin_amdgcn_mfma_f32_16x16x32_bf16(kf1, qf1, a, 0, 0, 0);
    s[nf] = a;
  }
  __builtin_amdgcn_s_setprio(0);
}

static __device__ __forceinline__ void maskdiag(f32x4 s[4], int wave, int cl, int g){
  const int qrl = wave * 16 + cl;
#pragma unroll
  for (int nf = 0; nf < 4; nf++)
#pragma unroll
    for (int r = 0; r < 4; r++)
      if (nf * 16 + g * 4 + r > qrl) s[nf][r] = -3e38f;
}

// online softmax (log2 domain, defer-max THR=8, tree reductions) + PV accumulate
static __device__ __forceinline__ void sm_pv(
    f32x4 s[4], f32x4 o[4], float& mrun, float& lrun,
    const u16* __restrict__ VtC, int cl, int g)
{
  // tree max (depth 4; clang fuses nested fmaxf into v_max3)
  const float t0 = fmaxf(fmaxf(s[0][0], s[0][1]), fmaxf(s[0][2], s[0][3]));
  const float t1 = fmaxf(fmaxf(s[1][0], s[1][1]), fmaxf(s[1][2], s[1][3]));
  const float t2 = fmaxf(fmaxf(s[2][0], s[2][1]), fmaxf(s[2][2], s[2][3]));
  const float t3 = fmaxf(fmaxf(s[3][0], s[3][1]), fmaxf(s[3][2], s[3][3]));
  float rmax = fmaxf(fmaxf(t0, t1), fmaxf(t2, t3));
  rmax = fmaxf(rmax, __shfl_xor(rmax, 16));
  rmax = fmaxf(rmax, __shfl_xor(rmax, 32));
  // defer-max: only rescale when the row max grew by >8 (P bounded by 2^8)
  if (!__all(rmax <= mrun + 8.0f)){
    const float mnew = fmaxf(mrun, rmax);
    const float alpha = exp2f(mrun - mnew);
    mrun = mnew;
    lrun *= alpha;
    const float a0 = __shfl(alpha, g * 4 + 0);
    const float a1 = __shfl(alpha, g * 4 + 1);
    const float a2 = __shfl(alpha, g * 4 + 2);
    const float a3 = __shfl(alpha, g * 4 + 3);
#pragma unroll
    for (int fo = 0; fo < 4; fo++){
      o[fo][0] *= a0; o[fo][1] *= a1; o[fo][2] *= a2; o[fo][3] *= a3;
    }
  }
#pragma unroll
  for (int nf = 0; nf < 4; nf++)
#pragma unroll
    for (int r = 0; r < 4; r++)
      s[nf][r] = exp2f(s[nf][r] - mrun);
  // tree sum
  const float u0 = (s[0][0] + s[0][1]) + (s[0][2] + s[0][3]);
  const float u1 = (s[1][0] + s[1][1]) + (s[1][2] + s[1][3]);
  const float u2 = (s[2][0] + s[2][1]) + (s[2][2] + s[2][3]);
  const float u3 = (s[3][0] + s[3][1]) + (s[3][2] + s[3][3]);
  float rs = (u0 + u1) + (u2 + u3);
  rs += __shfl_xor(rs, 16);
  rs += __shfl_xor(rs, 32);
  lrun += rs;

  u32 pk[8];
#pragma unroll
  for (int nf = 0; nf < 4; nf++){
    asm("v_cvt_pk_bf16_f32 %0, %1, %2" : "=v"(pk[2*nf  ]) : "v"(s[nf][0]), "v"(s[nf][1]));
    asm("v_cvt_pk_bf16_f32 %0, %1, %2" : "=v"(pk[2*nf+1]) : "v"(s[nf][2]), "v"(s[nf][3]));
  }
  __builtin_amdgcn_s_setprio(1);
#pragma unroll
  for (int nf = 0; nf < 4; nf++){
    union { u32 u[2]; bf16x4 v; } pa;
    pa.u[0] = pk[2*nf]; pa.u[1] = pk[2*nf+1];
#pragma unroll
    for (int fo = 0; fo < 4; fo++){
      const int d = fo * 16 + cl;
      const bf16x4 vf = *reinterpret_cast<const bf16x4*>(
          &VtC[d * 64 + (((nf * 4 + g) ^ (d & 7)) << 2)]);
      o[fo] = mfma16(pa.v, vf, o[fo]);
    }
  }
  __builtin_amdgcn_s_setprio(0);
}

// ---------------- causal flash attention: one KV sweep serves q-tiles {px, 31-px} ----------------
// TRIPLE-buffered staging, ONE barrier per tile (3-buffer hazard distance); vmcnt(4) keeps
// stage(t+1) in flight. 1D grid 1024, XCD swizzle: each XCD's 128 blocks share 8 bh's K/V.
__global__ __launch_bounds__(256) void k_flash(
    const u16* __restrict__ q, const u16* __restrict__ k,
    const u16* __restrict__ v, u16* __restrict__ ao)
{
  __shared__ u16 Ks[3][4096];   // [buf][kj*64 + swz-d], 16B-chunk swizzle: chunk' = chunk ^ (kj&7)
  __shared__ u16 Vt[3][4096];   // [buf][d*64 + swz-kj], 8B-chunk swizzle
  const int tid = threadIdx.x, wave = tid >> 6, lane = tid & 63;
  const int cl = lane & 15, g = lane >> 4;
  const int c0 = wave * 2;
  const int bid = blockIdx.x;
  const int swz = (bid & 7) * 128 + (bid >> 3);   // 1024/8 = 128 per XCD, bh-major
  const int bh = swz >> 4, px = swz & 15;
  const int qt1 = px, qt2 = NQT - 1 - px;
  const int ntot = qt2 + 1;
  const size_t base = (size_t)bh * NT * ND;
  const u16* kg0 = k + base;
  const u16* vg0 = v + base;

  // Q frags for both tiles: lane holds Q[q=cl][d=g*8+j]
  bf16x8 q1f0, q1f1, q2f0, q2f1;
  {
    const u16* qr1 = q + base + (size_t)(qt1 * 64 + wave * 16 + cl) * ND;
    q1f0 = *reinterpret_cast<const bf16x8*>(qr1 + g * 8);
    q1f1 = *reinterpret_cast<const bf16x8*>(qr1 + 32 + g * 8);
    const u16* qr2 = q + base + (size_t)(qt2 * 64 + wave * 16 + cl) * ND;
    q2f0 = *reinterpret_cast<const bf16x8*>(qr2 + g * 8);
    q2f1 = *reinterpret_cast<const bf16x8*>(qr2 + 32 + g * 8);
  }
  asm volatile("" : "+v"(q1f0), "+v"(q1f1), "+v"(q2f0), "+v"(q2f1));

  f32x4 o1[4] = {}, o2[4] = {};
  float m1 = -1e30f, l1 = 0.f, m2 = -1e30f, l2 = 0.f;

  // prologue: stage tile 0 -> buf 0 (4 gld_lds16 per wave)
  gld_lds16(&Ks[0][(c0    ) * 512], kg0 + (c0    ) * 512 + lane * 8);
  gld_lds16(&Ks[0][(c0 + 1) * 512], kg0 + (c0 + 1) * 512 + lane * 8);
  gld_lds16(&Vt[0][(c0    ) * 512], vg0 + (c0    ) * 512 + lane * 8);
  gld_lds16(&Vt[0][(c0 + 1) * 512], vg0 + (c0 + 1) * 512 + lane * 8);

  int cur = 0;
  for (int t = 0; t < ntot; ++t){
    const int nxt = (cur == 2) ? 0 : cur + 1;
    if (t + 1 < ntot){
      const u16* kg = kg0 + (size_t)(t + 1) * 4096;
      const u16* vg = vg0 + (size_t)(t + 1) * 4096;
      gld_lds16(&Ks[nxt][(c0    ) * 512], kg + (c0    ) * 512 + lane * 8);
      gld_lds16(&Ks[nxt][(c0 + 1) * 512], kg + (c0 + 1) * 512 + lane * 8);
      gld_lds16(&Vt[nxt][(c0    ) * 512], vg + (c0    ) * 512 + lane * 8);
      gld_lds16(&Vt[nxt][(c0 + 1) * 512], vg + (c0 + 1) * 512 + lane * 8);
      asm volatile("s_waitcnt vmcnt(4)" ::: "memory");   // own tile-t loads done; t+1 in flight
    } else {
      asm volatile("s_waitcnt vmcnt(0)" ::: "memory");
    }
    __builtin_amdgcn_sched_barrier(0);
    __builtin_amdgcn_s_barrier();    // the ONLY barrier per tile (3-buffer hazard distance)

    const u16* KsC = Ks[cur];
    const u16* VtC = Vt[cur];

    // state 2 (qt2): every tile
    {
      f32x4 s[4];
      qkt(KsC, q2f0, q2f1, cl, g, s);
      if (t == qt2) maskdiag(s, wave, cl, g);
      sm_pv(s, o2, m2, l2, VtC, cl, g);
    }
    // state 1 (qt1): tiles 0..qt1 (wave-uniform branch)
    if (t <= qt1){
      f32x4 s[4];
      qkt(KsC, q1f0, q1f1, cl, g, s);
      if (t == qt1) maskdiag(s, wave, cl, g);
      sm_pv(s, o1, m1, l1, VtC, cl, g);
    }
    cur = nxt;
  }

  // ---- epilogue: O/l for both q-tiles -> attn_out [B,T,C] bf16 ----
  float li1[4], li2[4];
#pragma unroll
  for (int r = 0; r < 4; r++){
    li1[r] = 1.0f / __shfl(l1, g * 4 + r);
    li2[r] = 1.0f / __shfl(l2, g * 4 + r);
  }
  const int b = bh >> 4, h = bh & 15;
#pragma unroll
  for (int fo = 0; fo < 4; fo++){
#pragma unroll
    for (int r = 0; r < 4; r++){
      const int c = h * 64 + fo * 16 + cl;
      const int t1 = qt1 * 64 + wave * 16 + g * 4 + r;
      ao[((size_t)b * NT + t1) * NC + c] = f2bf(o1[fo][r] * li1[r]);
      const int t2 = qt2 * 64 + wave * 16 + g * 4 + r;
      ao[((size_t)b * NT + t2) * NC + c] = f2bf(o2[fo][r] * li2[r]);
    }
  }
}

extern "C" void kernel_launch(void* const* d_in, const int* in_sizes, int n_in,
                              void* d_out, int out_size, void* d_ws, size_t ws_size,
                              hipStream_t stream){
  const float* x      = (const float*)d_in[0];
  const float* w_qkv  = (const float*)d_in[1];
  const float* b_qkv  = (const float*)d_in[2];
  const float* w_proj = (const float*)d_in[3];
  const float* b_proj = (const float*)d_in[4];
  float* out = (float*)d_out;

  u16* ws = (u16*)d_ws;
  u16* qb     = ws + 8388608;       //  [B,H,T,D] standard
  u16* kb     = ws + 16777216;      //  [B,H] x tiles, swizzled
  u16* vb     = ws + 25165824;      //  [B,H] x tiles, transposed+swizzled
  u16* aob    = ws + 33554432;      //  [B,T,C]
  u16* wqkvT  = ws + 41943040;      //  [3C,C]
  u16* wprojT = ws + 45088768;      //  [C,C]

  k_transpose_cast<<<dim3(N3C / 32, NC / 32), dim3(32, 8), 0, stream>>>(w_qkv, wqkvT, NC, N3C);
  k_transpose_cast<<<dim3(NC / 32, NC / 32), dim3(32, 8), 0, stream>>>(w_proj, wprojT, NC, NC);
  k_gemm_qkv<<<1536, 256, 0, stream>>>(x, wqkvT, b_qkv, qb, kb, vb);
  k_flash<<<1024, 256, 0, stream>>>(qb, kb, vb, aob);
  k_gemm_proj<<<512, 256, 0, stream>>>(aob, wprojT, b_proj, out);
}

// Round 23
// 214.173 us; speedup vs baseline: 1.1263x; 1.1263x over previous
//
#include <hip/hip_runtime.h>
#include <cstdint>

typedef unsigned short u16;
typedef uint32_t u32;
typedef __attribute__((ext_vector_type(8))) short bf16x8;
typedef __attribute__((ext_vector_type(4))) short bf16x4;
typedef __attribute__((ext_vector_type(4))) float f32x4;

#define NB 4
#define NT 2048
#define NC 1024
#define NH 16
#define ND 64
#define NM (NB*NT)      // 8192
#define N3C (3*NC)      // 3072
#define NQT (NT/64)     // 32 q-tiles per (b,h)

// Q scale: 1/sqrt(64) * log2(e)  (softmax runs in log2 domain -> exp2)
#define QSCALE 0.18033688011112042f

static __device__ __forceinline__ u16 f2bf(float f){
  union { float f; uint32_t u; } v; v.f = f;
  return (u16)((v.u + 0x7fffu + ((v.u >> 16) & 1u)) >> 16);
}

// async 16B global->LDS (LDS dest is wave-uniform base + lane*16)
static __device__ __forceinline__ void gld_lds16(void* lds, const void* g){
  auto lp = reinterpret_cast<__attribute__((address_space(3))) uint32_t*>(
      reinterpret_cast<uintptr_t>(lds));
  auto gp = reinterpret_cast<__attribute__((address_space(1))) uint32_t*>(
      reinterpret_cast<uintptr_t>(g));
  __builtin_amdgcn_global_load_lds(gp, lp, 16, 0, 0);
}

static __device__ __forceinline__ f32x4 mfma16(bf16x4 a, bf16x4 b, f32x4 c){
#if __has_builtin(__builtin_amdgcn_mfma_f32_16x16x16bf16_1k)
  return __builtin_amdgcn_mfma_f32_16x16x16bf16_1k(a, b, c, 0, 0, 0);
#else
  asm("v_mfma_f32_16x16x16_bf16 %0, %1, %2, %0" : "+v"(c) : "v"(a), "v"(b));
  return c;
#endif
}

// ---------------- elementwise cast fp32 -> bf16 ----------------
__global__ __launch_bounds__(256) void k_cast(const float* __restrict__ in,
                                              u16* __restrict__ out){
  const int i = (blockIdx.x * 256 + threadIdx.x) * 4;
  const float4 vv = *reinterpret_cast<const float4*>(in + i);
  union { u16 s[4]; uint64_t u; } pk;
  pk.s[0] = f2bf(vv.x); pk.s[1] = f2bf(vv.y);
  pk.s[2] = f2bf(vv.z); pk.s[3] = f2bf(vv.w);
  *reinterpret_cast<uint64_t*>(out + i) = pk.u;
}

// ---------------- tiled transpose + cast: in[R][Cc] fp32 -> out[Cc][R] bf16 ----------------
__global__ __launch_bounds__(256) void k_transpose_cast(const float* __restrict__ in,
                                                        u16* __restrict__ out,
                                                        int R, int Cc){
  __shared__ float tile[32][33];
  const int bx = blockIdx.x * 32, by = blockIdx.y * 32;
  const int tx = threadIdx.x, ty = threadIdx.y;
#pragma unroll
  for (int i = 0; i < 32; i += 8)
    tile[ty + i][tx] = in[(size_t)(by + ty + i) * Cc + bx + tx];
  __syncthreads();
#pragma unroll
  for (int i = 0; i < 32; i += 8)
    out[(size_t)(bx + ty + i) * R + by + tx] = f2bf(tile[tx][ty + i]);
}

// ---------------- shared GEMM main loop: C[128x128] tile, BK=32 (r9-proven) ----------------
static __device__ __forceinline__ void gemm_mainloop(
    const u16* __restrict__ A, const u16* __restrict__ Bt, int K,
    int m0, int n0, u16* As, u16* Bs, f32x4 acc[4][4])
{
  const int tid = threadIdx.x;
  const int wave = tid >> 6, lane = tid & 63;
  const int wm = wave >> 1, wn = wave & 1;
  const int o0 = tid * 8, o1 = o0 + 2048;           // elem offsets in the 128x32 tile
  const u16* Ag0 = A  + (size_t)(m0 + (o0 >> 5)) * K + (o0 & 31);
  const u16* Ag1 = A  + (size_t)(m0 + (o1 >> 5)) * K + (o1 & 31);
  const u16* Bg0 = Bt + (size_t)(n0 + (o0 >> 5)) * K + (o0 & 31);
  const u16* Bg1 = Bt + (size_t)(n0 + (o1 >> 5)) * K + (o1 & 31);
  u16* AsW = As + wave * 512;   // wave-uniform LDS base (1024 B per wave)
  u16* BsW = Bs + wave * 512;
  const int kb = (lane >> 4) * 8, rl = lane & 15;

  for (int kt = 0; kt < K; kt += 32){
    gld_lds16(AsW,        Ag0 + kt);
    gld_lds16(AsW + 2048, Ag1 + kt);
    gld_lds16(BsW,        Bg0 + kt);
    gld_lds16(BsW + 2048, Bg1 + kt);
    __syncthreads();
    bf16x8 af[4], bfr[4];
#pragma unroll
    for (int i = 0; i < 4; i++){
      af[i]  = *reinterpret_cast<const bf16x8*>(&As[(wm * 64 + i * 16 + rl) * 32 + kb]);
      bfr[i] = *reinterpret_cast<const bf16x8*>(&Bs[(wn * 64 + i * 16 + rl) * 32 + kb]);
    }
#pragma unroll
    for (int i = 0; i < 4; i++)
#pragma unroll
      for (int j = 0; j < 4; j++)
        acc[i][j] = __builtin_amdgcn_mfma_f32_16x16x32_bf16(af[i], bfr[j], acc[i][j], 0, 0, 0);
    __syncthreads();
  }
}

// ---------------- GEMM 1: x @ w_qkv + b_qkv -> Q (scaled), K (swizzled), V (transposed+swizzled) ----------------
// 1D grid 1536, XCD swizzle (T1): each XCD gets 8 contiguous M-row panels (A L2-resident).
// Q: [b,h,t,d] standard, values * QSCALE
// K: per (b,h): tile kt (4096 elems): (t&63)*64 + (d ^ ((t&7)<<3))
// V: per (b,h): tile kt (4096 elems): d*64 + (((t>>2)&15 ^ (d&7))<<2) + (t&3)   [transposed]
__global__ __launch_bounds__(256) void k_gemm_qkv(
    const u16* __restrict__ A, const u16* __restrict__ Bt,
    const float* __restrict__ bias,
    u16* __restrict__ qo, u16* __restrict__ ko, u16* __restrict__ vo)
{
  __shared__ u16 As[128 * 32], Bs[128 * 32];
  f32x4 acc[4][4] = {};
  const int bid = blockIdx.x;
  const int swz = (bid & 7) * 192 + (bid >> 3);   // 1536/8 = 192 per XCD, m-major chunks
  const int m0 = (swz / 24) * 128, n0 = (swz % 24) * 128;
  gemm_mainloop(A, Bt, NC, m0, n0, As, Bs, acc);

  const int tid = threadIdx.x;
  const int wave = tid >> 6, lane = tid & 63;
  const int wm = wave >> 1, wn = wave & 1;
  const int rl = lane & 15, rg = lane >> 4;
  const int which = n0 >> 10;   // uniform per block: 0=Q 1=K 2=V
  if (which == 2){
    // V: pack 4 consecutive t (r=0..3, t&3=r) into one 8B store
#pragma unroll
    for (int j = 0; j < 4; j++){
      const int n = n0 + wn * 64 + j * 16 + rl;
      const int cc = n & 1023;
      const int h = cc >> 6, d = cc & 63;
      const float bb = bias[n];
#pragma unroll
      for (int i = 0; i < 4; i++){
        const int mb = m0 + wm * 64 + i * 16 + rg * 4;
        const int b = mb >> 11, t0 = mb & 2047;
        const size_t bhb = ((size_t)(b * NH + h)) * NT * ND;
        union { u16 s[4]; uint64_t u; } pk4;
#pragma unroll
        for (int r = 0; r < 4; r++) pk4.s[r] = f2bf(acc[i][j][r] + bb);
        *reinterpret_cast<uint64_t*>(
          &vo[bhb + (size_t)(t0 >> 6) * 4096 + d * 64 + ((((t0 >> 2) & 15) ^ (d & 7)) << 2)]) = pk4.u;
      }
    }
  } else {
#pragma unroll
    for (int j = 0; j < 4; j++){
      const int n = n0 + wn * 64 + j * 16 + rl;
      const int cc = n & 1023;
      const int h = cc >> 6, d = cc & 63;
      const float bb = bias[n];
#pragma unroll
      for (int i = 0; i < 4; i++){
#pragma unroll
        for (int r = 0; r < 4; r++){
          const int m = m0 + wm * 64 + i * 16 + rg * 4 + r;
          const int b = m >> 11, t = m & 2047;
          const size_t bhb = ((size_t)(b * NH + h)) * NT * ND;
          const float val = acc[i][j][r] + bb;
          if (which == 0){
            qo[bhb + (size_t)t * ND + d] = f2bf(val * QSCALE);
          } else {
            ko[bhb + (size_t)(t >> 6) * 4096 + (t & 63) * 64 + (d ^ ((t & 7) << 3))] = f2bf(val);
          }
        }
      }
    }
  }
}

// ---------------- GEMM 2: attn_out @ w_proj + b_proj -> fp32 out ----------------
// 1D grid 512, XCD swizzle: each XCD gets an 8x8 tile chunk (A 2MB + B 2MB ~ L2).
__global__ __launch_bounds__(256) void k_gemm_proj(
    const u16* __restrict__ A, const u16* __restrict__ Bt,
    const float* __restrict__ bias, float* __restrict__ out)
{
  __shared__ u16 As[128 * 32], Bs[128 * 32];
  f32x4 acc[4][4] = {};
  const int bid = blockIdx.x;
  const int swz = (bid & 7) * 64 + (bid >> 3);    // 512/8 = 64 per XCD
  const int m0 = (swz >> 3) * 128, n0 = (swz & 7) * 128;
  gemm_mainloop(A, Bt, NC, m0, n0, As, Bs, acc);

  const int tid = threadIdx.x;
  const int wave = tid >> 6, lane = tid & 63;
  const int wm = wave >> 1, wn = wave & 1;
  const int rl = lane & 15, rg = lane >> 4;
#pragma unroll
  for (int i = 0; i < 4; i++){
#pragma unroll
    for (int r = 0; r < 4; r++){
      const int m = m0 + wm * 64 + i * 16 + rg * 4 + r;
#pragma unroll
      for (int j = 0; j < 4; j++){
        const int n = n0 + wn * 64 + j * 16 + rl;
        out[(size_t)m * NC + n] = acc[i][j][r] + bias[n];
      }
    }
  }
}

// ---------------- flash helpers (round-9 proven) ----------------
// S^T = K Q^T : s[nf] holds S^T[k = nf*16 + g*4 + r][q = cl]
static __device__ __forceinline__ void qkt(const u16* __restrict__ KsC,
                                           bf16x8 qf0, bf16x8 qf1,
                                           int cl, int g, f32x4 s[4])
{
  __builtin_amdgcn_s_setprio(1);
#pragma unroll
  for (int nf = 0; nf < 4; nf++){
    const int kj = nf * 16 + cl;
    const u16* krow = &KsC[kj * 64];
    const bf16x8 kf0 = *reinterpret_cast<const bf16x8*>(&krow[((0 + g) ^ (kj & 7)) * 8]);
    const bf16x8 kf1 = *reinterpret_cast<const bf16x8*>(&krow[((4 + g) ^ (kj & 7)) * 8]);
    f32x4 a = {};
    a = __builtin_amdgcn_mfma_f32_16x16x32_bf16(kf0, qf0, a, 0, 0, 0);
    a = __builtin_amdgcn_mfma_f32_16x16x32_bf16(kf1, qf1, a, 0, 0, 0);
    s[nf] = a;
  }
  __builtin_amdgcn_s_setprio(0);
}

static __device__ __forceinline__ void maskdiag(f32x4 s[4], int wave, int cl, int g){
  const int qrl = wave * 16 + cl;
#pragma unroll
  for (int nf = 0; nf < 4; nf++)
#pragma unroll
    for (int r = 0; r < 4; r++)
      if (nf * 16 + g * 4 + r > qrl) s[nf][r] = -3e38f;
}

// online softmax (log2 domain, defer-max THR=8) + PV accumulate
static __device__ __forceinline__ void sm_pv(
    f32x4 s[4], f32x4 o[4], float& mrun, float& lrun,
    const u16* __restrict__ VtC, int cl, int g)
{
  float rmax = -3e38f;
#pragma unroll
  for (int nf = 0; nf < 4; nf++)
#pragma unroll
    for (int r = 0; r < 4; r++) rmax = fmaxf(rmax, s[nf][r]);
  rmax = fmaxf(rmax, __shfl_xor(rmax, 16));
  rmax = fmaxf(rmax, __shfl_xor(rmax, 32));
  // defer-max: only rescale when the row max grew by >8 (P bounded by 2^8)
  if (!__all(rmax <= mrun + 8.0f)){
    const float mnew = fmaxf(mrun, rmax);
    const float alpha = exp2f(mrun - mnew);
    mrun = mnew;
    lrun *= alpha;
    const float a0 = __shfl(alpha, g * 4 + 0);
    const float a1 = __shfl(alpha, g * 4 + 1);
    const float a2 = __shfl(alpha, g * 4 + 2);
    const float a3 = __shfl(alpha, g * 4 + 3);
#pragma unroll
    for (int fo = 0; fo < 4; fo++){
      o[fo][0] *= a0; o[fo][1] *= a1; o[fo][2] *= a2; o[fo][3] *= a3;
    }
  }
  float rs = 0.f;
#pragma unroll
  for (int nf = 0; nf < 4; nf++)
#pragma unroll
    for (int r = 0; r < 4; r++){
      s[nf][r] = exp2f(s[nf][r] - mrun);
      rs += s[nf][r];
    }
  rs += __shfl_xor(rs, 16);
  rs += __shfl_xor(rs, 32);
  lrun += rs;

  u32 pk[8];
#pragma unroll
  for (int nf = 0; nf < 4; nf++){
    asm("v_cvt_pk_bf16_f32 %0, %1, %2" : "=v"(pk[2*nf  ]) : "v"(s[nf][0]), "v"(s[nf][1]));
    asm("v_cvt_pk_bf16_f32 %0, %1, %2" : "=v"(pk[2*nf+1]) : "v"(s[nf][2]), "v"(s[nf][3]));
  }
  __builtin_amdgcn_s_setprio(1);
#pragma unroll
  for (int nf = 0; nf < 4; nf++){
    union { u32 u[2]; bf16x4 v; } pa;
    pa.u[0] = pk[2*nf]; pa.u[1] = pk[2*nf+1];
#pragma unroll
    for (int fo = 0; fo < 4; fo++){
      const int d = fo * 16 + cl;
      const bf16x4 vf = *reinterpret_cast<const bf16x4*>(
          &VtC[d * 64 + (((nf * 4 + g) ^ (d & 7)) << 2)]);
      o[fo] = mfma16(pa.v, vf, o[fo]);
    }
  }
  __builtin_amdgcn_s_setprio(0);
}

// ---------------- causal flash attention: one KV sweep serves q-tiles {px, 31-px} ----------------
// TRIPLE-buffered staging, ONE barrier per tile (3-buffer hazard distance); vmcnt(4) keeps
// stage(t+1) in flight. 1D grid 1024, XCD swizzle: each XCD's 128 blocks share 8 bh's K/V.
__global__ __launch_bounds__(256) void k_flash(
    const u16* __restrict__ q, const u16* __restrict__ k,
    const u16* __restrict__ v, u16* __restrict__ ao)
{
  __shared__ u16 Ks[3][4096];   // [buf][kj*64 + swz-d], 16B-chunk swizzle: chunk' = chunk ^ (kj&7)
  __shared__ u16 Vt[3][4096];   // [buf][d*64 + swz-kj], 8B-chunk swizzle
  const int tid = threadIdx.x, wave = tid >> 6, lane = tid & 63;
  const int cl = lane & 15, g = lane >> 4;
  const int c0 = wave * 2;
  const int bid = blockIdx.x;
  const int swz = (bid & 7) * 128 + (bid >> 3);   // 1024/8 = 128 per XCD, bh-major
  const int bh = swz >> 4, px = swz & 15;
  const int qt1 = px, qt2 = NQT - 1 - px;
  const int ntot = qt2 + 1;
  const size_t base = (size_t)bh * NT * ND;
  const u16* kg0 = k + base;
  const u16* vg0 = v + base;

  // Q frags for both tiles: lane holds Q[q=cl][d=g*8+j]
  bf16x8 q1f0, q1f1, q2f0, q2f1;
  {
    const u16* qr1 = q + base + (size_t)(qt1 * 64 + wave * 16 + cl) * ND;
    q1f0 = *reinterpret_cast<const bf16x8*>(qr1 + g * 8);
    q1f1 = *reinterpret_cast<const bf16x8*>(qr1 + 32 + g * 8);
    const u16* qr2 = q + base + (size_t)(qt2 * 64 + wave * 16 + cl) * ND;
    q2f0 = *reinterpret_cast<const bf16x8*>(qr2 + g * 8);
    q2f1 = *reinterpret_cast<const bf16x8*>(qr2 + 32 + g * 8);
  }
  asm volatile("" : "+v"(q1f0), "+v"(q1f1), "+v"(q2f0), "+v"(q2f1));

  f32x4 o1[4] = {}, o2[4] = {};
  float m1 = -1e30f, l1 = 0.f, m2 = -1e30f, l2 = 0.f;

  // prologue: stage tile 0 -> buf 0 (4 gld_lds16 per wave)
  gld_lds16(&Ks[0][(c0    ) * 512], kg0 + (c0    ) * 512 + lane * 8);
  gld_lds16(&Ks[0][(c0 + 1) * 512], kg0 + (c0 + 1) * 512 + lane * 8);
  gld_lds16(&Vt[0][(c0    ) * 512], vg0 + (c0    ) * 512 + lane * 8);
  gld_lds16(&Vt[0][(c0 + 1) * 512], vg0 + (c0 + 1) * 512 + lane * 8);

  int cur = 0;
  for (int t = 0; t < ntot; ++t){
    const int nxt = (cur == 2) ? 0 : cur + 1;
    if (t + 1 < ntot){
      const u16* kg = kg0 + (size_t)(t + 1) * 4096;
      const u16* vg = vg0 + (size_t)(t + 1) * 4096;
      gld_lds16(&Ks[nxt][(c0    ) * 512], kg + (c0    ) * 512 + lane * 8);
      gld_lds16(&Ks[nxt][(c0 + 1) * 512], kg + (c0 + 1) * 512 + lane * 8);
      gld_lds16(&Vt[nxt][(c0    ) * 512], vg + (c0    ) * 512 + lane * 8);
      gld_lds16(&Vt[nxt][(c0 + 1) * 512], vg + (c0 + 1) * 512 + lane * 8);
      asm volatile("s_waitcnt vmcnt(4)" ::: "memory");   // own tile-t loads done; t+1 in flight
    } else {
      asm volatile("s_waitcnt vmcnt(0)" ::: "memory");
    }
    __builtin_amdgcn_sched_barrier(0);
    __builtin_amdgcn_s_barrier();    // the ONLY barrier per tile (3-buffer hazard distance)

    const u16* KsC = Ks[cur];
    const u16* VtC = Vt[cur];

    // state 2 (qt2): every tile
    {
      f32x4 s[4];
      qkt(KsC, q2f0, q2f1, cl, g, s);
      if (t == qt2) maskdiag(s, wave, cl, g);
      sm_pv(s, o2, m2, l2, VtC, cl, g);
    }
    // state 1 (qt1): tiles 0..qt1 (wave-uniform branch)
    if (t <= qt1){
      f32x4 s[4];
      qkt(KsC, q1f0, q1f1, cl, g, s);
      if (t == qt1) maskdiag(s, wave, cl, g);
      sm_pv(s, o1, m1, l1, VtC, cl, g);
    }
    cur = nxt;
  }

  // ---- epilogue: O/l for both q-tiles -> attn_out [B,T,C] bf16 ----
  float li1[4], li2[4];
#pragma unroll
  for (int r = 0; r < 4; r++){
    li1[r] = 1.0f / __shfl(l1, g * 4 + r);
    li2[r] = 1.0f / __shfl(l2, g * 4 + r);
  }
  const int b = bh >> 4, h = bh & 15;
#pragma unroll
  for (int fo = 0; fo < 4; fo++){
#pragma unroll
    for (int r = 0; r < 4; r++){
      const int c = h * 64 + fo * 16 + cl;
      const int t1 = qt1 * 64 + wave * 16 + g * 4 + r;
      ao[((size_t)b * NT + t1) * NC + c] = f2bf(o1[fo][r] * li1[r]);
      const int t2 = qt2 * 64 + wave * 16 + g * 4 + r;
      ao[((size_t)b * NT + t2) * NC + c] = f2bf(o2[fo][r] * li2[r]);
    }
  }
}

extern "C" void kernel_launch(void* const* d_in, const int* in_sizes, int n_in,
                              void* d_out, int out_size, void* d_ws, size_t ws_size,
                              hipStream_t stream){
  const float* x      = (const float*)d_in[0];
  const float* w_qkv  = (const float*)d_in[1];
  const float* b_qkv  = (const float*)d_in[2];
  const float* w_proj = (const float*)d_in[3];
  const float* b_proj = (const float*)d_in[4];
  float* out = (float*)d_out;

  u16* ws = (u16*)d_ws;
  u16* xb     = ws;                 //  [B,T,C] bf16
  u16* qb     = ws + 8388608;       //  [B,H,T,D] standard
  u16* kb     = ws + 16777216;      //  [B,H] x tiles, swizzled
  u16* vb     = ws + 25165824;      //  [B,H] x tiles, transposed+swizzled
  u16* aob    = ws + 33554432;      //  [B,T,C]
  u16* wqkvT  = ws + 41943040;      //  [3C,C]
  u16* wprojT = ws + 45088768;      //  [C,C]

  k_cast<<<8388608 / 1024, 256, 0, stream>>>(x, xb);
  k_transpose_cast<<<dim3(N3C / 32, NC / 32), dim3(32, 8), 0, stream>>>(w_qkv, wqkvT, NC, N3C);
  k_transpose_cast<<<dim3(NC / 32, NC / 32), dim3(32, 8), 0, stream>>>(w_proj, wprojT, NC, NC);
  k_gemm_qkv<<<1536, 256, 0, stream>>>(xb, wqkvT, b_qkv, qb, kb, vb);
  k_flash<<<1024, 256, 0, stream>>>(qb, kb, vb, aob);
  k_gemm_proj<<<512, 256, 0, stream>>>(aob, wprojT, b_proj, out);
}

// Round 24
// 210.835 us; speedup vs baseline: 1.1441x; 1.0158x over previous
//
#include <hip/hip_runtime.h>
#include <cstdint>

typedef unsigned short u16;
typedef uint32_t u32;
typedef __attribute__((ext_vector_type(8))) short bf16x8;
typedef __attribute__((ext_vector_type(4))) short bf16x4;
typedef __attribute__((ext_vector_type(4))) float f32x4;

#define NB 4
#define NT 2048
#define NC 1024
#define NH 16
#define ND 64
#define NM (NB*NT)      // 8192
#define N3C (3*NC)      // 3072
#define NQT (NT/64)     // 32 q-tiles per (b,h)

// Q scale: 1/sqrt(64) * log2(e)  (softmax runs in log2 domain -> exp2)
#define QSCALE 0.18033688011112042f

static __device__ __forceinline__ u16 f2bf(float f){
  union { float f; uint32_t u; } v; v.f = f;
  return (u16)((v.u + 0x7fffu + ((v.u >> 16) & 1u)) >> 16);
}

// async 16B global->LDS (LDS dest is wave-uniform base + lane*16)
static __device__ __forceinline__ void gld_lds16(void* lds, const void* g){
  auto lp = reinterpret_cast<__attribute__((address_space(3))) uint32_t*>(
      reinterpret_cast<uintptr_t>(lds));
  auto gp = reinterpret_cast<__attribute__((address_space(1))) uint32_t*>(
      reinterpret_cast<uintptr_t>(g));
  __builtin_amdgcn_global_load_lds(gp, lp, 16, 0, 0);
}

static __device__ __forceinline__ f32x4 mfma16(bf16x4 a, bf16x4 b, f32x4 c){
#if __has_builtin(__builtin_amdgcn_mfma_f32_16x16x16bf16_1k)
  return __builtin_amdgcn_mfma_f32_16x16x16bf16_1k(a, b, c, 0, 0, 0);
#else
  asm("v_mfma_f32_16x16x16_bf16 %0, %1, %2, %0" : "+v"(c) : "v"(a), "v"(b));
  return c;
#endif
}

// ---------------- fused prep: cast x -> bf16 (blocks 0..8191),
// transpose+cast w_qkv (blocks 8192..11263), w_proj (blocks 11264..12287) ----------------
static __device__ __forceinline__ void do_transpose(const float* __restrict__ in,
                                                    u16* __restrict__ out,
                                                    int R, int Cc, int bx32, int by32){
  __shared__ float tile[32][33];
  const int bx = bx32 * 32, by = by32 * 32;
  const int tx = threadIdx.x & 31, ty = threadIdx.x >> 5;  // 32x8 from 256 linear
#pragma unroll
  for (int i = 0; i < 32; i += 8)
    tile[ty + i][tx] = in[(size_t)(by + ty + i) * Cc + bx + tx];
  __syncthreads();
#pragma unroll
  for (int i = 0; i < 32; i += 8)
    out[(size_t)(bx + ty + i) * R + by + tx] = f2bf(tile[tx][ty + i]);
}

__global__ __launch_bounds__(256) void k_prep(const float* __restrict__ x,
                                              u16* __restrict__ xb,
                                              const float* __restrict__ w_qkv,
                                              u16* __restrict__ wqkvT,
                                              const float* __restrict__ w_proj,
                                              u16* __restrict__ wprojT){
  const int bid = blockIdx.x;
  if (bid < 8192){
    const int i = (bid * 256 + threadIdx.x) * 4;
    const float4 vv = *reinterpret_cast<const float4*>(x + i);
    union { u16 s[4]; uint64_t u; } pk;
    pk.s[0] = f2bf(vv.x); pk.s[1] = f2bf(vv.y);
    pk.s[2] = f2bf(vv.z); pk.s[3] = f2bf(vv.w);
    *reinterpret_cast<uint64_t*>(xb + i) = pk.u;
  } else if (bid < 8192 + 3072){
    const int t = bid - 8192;            // w_qkv: (96 x, 32 y) tiles
    do_transpose(w_qkv, wqkvT, NC, N3C, t % 96, t / 96);
  } else {
    const int t = bid - 8192 - 3072;     // w_proj: (32 x, 32 y) tiles
    do_transpose(w_proj, wprojT, NC, NC, t % 32, t / 32);
  }
}

// ---------------- shared GEMM main loop: C[128x128] tile, BK=32 (r9-proven) ----------------
static __device__ __forceinline__ void gemm_mainloop(
    const u16* __restrict__ A, const u16* __restrict__ Bt, int K,
    int m0, int n0, u16* As, u16* Bs, f32x4 acc[4][4])
{
  const int tid = threadIdx.x;
  const int wave = tid >> 6, lane = tid & 63;
  const int wm = wave >> 1, wn = wave & 1;
  const int o0 = tid * 8, o1 = o0 + 2048;           // elem offsets in the 128x32 tile
  const u16* Ag0 = A  + (size_t)(m0 + (o0 >> 5)) * K + (o0 & 31);
  const u16* Ag1 = A  + (size_t)(m0 + (o1 >> 5)) * K + (o1 & 31);
  const u16* Bg0 = Bt + (size_t)(n0 + (o0 >> 5)) * K + (o0 & 31);
  const u16* Bg1 = Bt + (size_t)(n0 + (o1 >> 5)) * K + (o1 & 31);
  u16* AsW = As + wave * 512;   // wave-uniform LDS base (1024 B per wave)
  u16* BsW = Bs + wave * 512;
  const int kb = (lane >> 4) * 8, rl = lane & 15;

  for (int kt = 0; kt < K; kt += 32){
    gld_lds16(AsW,        Ag0 + kt);
    gld_lds16(AsW + 2048, Ag1 + kt);
    gld_lds16(BsW,        Bg0 + kt);
    gld_lds16(BsW + 2048, Bg1 + kt);
    __syncthreads();
    bf16x8 af[4], bfr[4];
#pragma unroll
    for (int i = 0; i < 4; i++){
      af[i]  = *reinterpret_cast<const bf16x8*>(&As[(wm * 64 + i * 16 + rl) * 32 + kb]);
      bfr[i] = *reinterpret_cast<const bf16x8*>(&Bs[(wn * 64 + i * 16 + rl) * 32 + kb]);
    }
#pragma unroll
    for (int i = 0; i < 4; i++)
#pragma unroll
      for (int j = 0; j < 4; j++)
        acc[i][j] = __builtin_amdgcn_mfma_f32_16x16x32_bf16(af[i], bfr[j], acc[i][j], 0, 0, 0);
    __syncthreads();
  }
}

// ---------------- GEMM 1: x @ w_qkv + b_qkv -> Q (scaled), K (swizzled), V (transposed+swizzled) ----------------
// 1D grid 1536, XCD swizzle (T1): each XCD gets 8 contiguous M-row panels (A L2-resident).
__global__ __launch_bounds__(256) void k_gemm_qkv(
    const u16* __restrict__ A, const u16* __restrict__ Bt,
    const float* __restrict__ bias,
    u16* __restrict__ qo, u16* __restrict__ ko, u16* __restrict__ vo)
{
  __shared__ u16 As[128 * 32], Bs[128 * 32];
  f32x4 acc[4][4] = {};
  const int bid = blockIdx.x;
  const int swz = (bid & 7) * 192 + (bid >> 3);   // 1536/8 = 192 per XCD, m-major chunks
  const int m0 = (swz / 24) * 128, n0 = (swz % 24) * 128;
  gemm_mainloop(A, Bt, NC, m0, n0, As, Bs, acc);

  const int tid = threadIdx.x;
  const int wave = tid >> 6, lane = tid & 63;
  const int wm = wave >> 1, wn = wave & 1;
  const int rl = lane & 15, rg = lane >> 4;
  const int which = n0 >> 10;   // uniform per block: 0=Q 1=K 2=V
  if (which == 2){
    // V: pack 4 consecutive t (r=0..3, t&3=r) into one 8B store
#pragma unroll
    for (int j = 0; j < 4; j++){
      const int n = n0 + wn * 64 + j * 16 + rl;
      const int cc = n & 1023;
      const int h = cc >> 6, d = cc & 63;
      const float bb = bias[n];
#pragma unroll
      for (int i = 0; i < 4; i++){
        const int mb = m0 + wm * 64 + i * 16 + rg * 4;
        const int b = mb >> 11, t0 = mb & 2047;
        const size_t bhb = ((size_t)(b * NH + h)) * NT * ND;
        union { u16 s[4]; uint64_t u; } pk4;
#pragma unroll
        for (int r = 0; r < 4; r++) pk4.s[r] = f2bf(acc[i][j][r] + bb);
        *reinterpret_cast<uint64_t*>(
          &vo[bhb + (size_t)(t0 >> 6) * 4096 + d * 64 + ((((t0 >> 2) & 15) ^ (d & 7)) << 2)]) = pk4.u;
      }
    }
  } else {
#pragma unroll
    for (int j = 0; j < 4; j++){
      const int n = n0 + wn * 64 + j * 16 + rl;
      const int cc = n & 1023;
      const int h = cc >> 6, d = cc & 63;
      const float bb = bias[n];
#pragma unroll
      for (int i = 0; i < 4; i++){
#pragma unroll
        for (int r = 0; r < 4; r++){
          const int m = m0 + wm * 64 + i * 16 + rg * 4 + r;
          const int b = m >> 11, t = m & 2047;
          const size_t bhb = ((size_t)(b * NH + h)) * NT * ND;
          const float val = acc[i][j][r] + bb;
          if (which == 0){
            qo[bhb + (size_t)t * ND + d] = f2bf(val * QSCALE);
          } else {
            ko[bhb + (size_t)(t >> 6) * 4096 + (t & 63) * 64 + (d ^ ((t & 7) << 3))] = f2bf(val);
          }
        }
      }
    }
  }
}

// ---------------- GEMM 2: attn_out @ w_proj + b_proj -> fp32 out ----------------
// 1D grid 512, XCD swizzle: each XCD gets an 8x8 tile chunk (A 2MB + B 2MB ~ L2).
__global__ __launch_bounds__(256) void k_gemm_proj(
    const u16* __restrict__ A, const u16* __restrict__ Bt,
    const float* __restrict__ bias, float* __restrict__ out)
{
  __shared__ u16 As[128 * 32], Bs[128 * 32];
  f32x4 acc[4][4] = {};
  const int bid = blockIdx.x;
  const int swz = (bid & 7) * 64 + (bid >> 3);    // 512/8 = 64 per XCD
  const int m0 = (swz >> 3) * 128, n0 = (swz & 7) * 128;
  gemm_mainloop(A, Bt, NC, m0, n0, As, Bs, acc);

  const int tid = threadIdx.x;
  const int wave = tid >> 6, lane = tid & 63;
  const int wm = wave >> 1, wn = wave & 1;
  const int rl = lane & 15, rg = lane >> 4;
#pragma unroll
  for (int i = 0; i < 4; i++){
#pragma unroll
    for (int r = 0; r < 4; r++){
      const int m = m0 + wm * 64 + i * 16 + rg * 4 + r;
#pragma unroll
      for (int j = 0; j < 4; j++){
        const int n = n0 + wn * 64 + j * 16 + rl;
        out[(size_t)m * NC + n] = acc[i][j][r] + bias[n];
      }
    }
  }
}

// ---------------- flash helpers (round-9 proven) ----------------
// S^T = K Q^T : s[nf] holds S^T[k = nf*16 + g*4 + r][q = cl]
static __device__ __forceinline__ void qkt(const u16* __restrict__ KsC,
                                           bf16x8 qf0, bf16x8 qf1,
                                           int cl, int g, f32x4 s[4])
{
  __builtin_amdgcn_s_setprio(1);
#pragma unroll
  for (int nf = 0; nf < 4; nf++){
    const int kj = nf * 16 + cl;
    const u16* krow = &KsC[kj * 64];
    const bf16x8 kf0 = *reinterpret_cast<const bf16x8*>(&krow[((0 + g) ^ (kj & 7)) * 8]);
    const bf16x8 kf1 = *reinterpret_cast<const bf16x8*>(&krow[((4 + g) ^ (kj & 7)) * 8]);
    f32x4 a = {};
    a = __builtin_amdgcn_mfma_f32_16x16x32_bf16(kf0, qf0, a, 0, 0, 0);
    a = __builtin_amdgcn_mfma_f32_16x16x32_bf16(kf1, qf1, a, 0, 0, 0);
    s[nf] = a;
  }
  __builtin_amdgcn_s_setprio(0);
}

static __device__ __forceinline__ void maskdiag(f32x4 s[4], int wave, int cl, int g){
  const int qrl = wave * 16 + cl;
#pragma unroll
  for (int nf = 0; nf < 4; nf++)
#pragma unroll
    for (int r = 0; r < 4; r++)
      if (nf * 16 + g * 4 + r > qrl) s[nf][r] = -3e38f;
}

// online softmax (log2 domain, defer-max THR=8) + PV accumulate
static __device__ __forceinline__ void sm_pv(
    f32x4 s[4], f32x4 o[4], float& mrun, float& lrun,
    const u16* __restrict__ VtC, int cl, int g)
{
  float rmax = -3e38f;
#pragma unroll
  for (int nf = 0; nf < 4; nf++)
#pragma unroll
    for (int r = 0; r < 4; r++) rmax = fmaxf(rmax, s[nf][r]);
  rmax = fmaxf(rmax, __shfl_xor(rmax, 16));
  rmax = fmaxf(rmax, __shfl_xor(rmax, 32));
  // defer-max: only rescale when the row max grew by >8 (P bounded by 2^8)
  if (!__all(rmax <= mrun + 8.0f)){
    const float mnew = fmaxf(mrun, rmax);
    const float alpha = exp2f(mrun - mnew);
    mrun = mnew;
    lrun *= alpha;
    const float a0 = __shfl(alpha, g * 4 + 0);
    const float a1 = __shfl(alpha, g * 4 + 1);
    const float a2 = __shfl(alpha, g * 4 + 2);
    const float a3 = __shfl(alpha, g * 4 + 3);
#pragma unroll
    for (int fo = 0; fo < 4; fo++){
      o[fo][0] *= a0; o[fo][1] *= a1; o[fo][2] *= a2; o[fo][3] *= a3;
    }
  }
  float rs = 0.f;
#pragma unroll
  for (int nf = 0; nf < 4; nf++)
#pragma unroll
    for (int r = 0; r < 4; r++){
      s[nf][r] = exp2f(s[nf][r] - mrun);
      rs += s[nf][r];
    }
  rs += __shfl_xor(rs, 16);
  rs += __shfl_xor(rs, 32);
  lrun += rs;

  u32 pk[8];
#pragma unroll
  for (int nf = 0; nf < 4; nf++){
    asm("v_cvt_pk_bf16_f32 %0, %1, %2" : "=v"(pk[2*nf  ]) : "v"(s[nf][0]), "v"(s[nf][1]));
    asm("v_cvt_pk_bf16_f32 %0, %1, %2" : "=v"(pk[2*nf+1]) : "v"(s[nf][2]), "v"(s[nf][3]));
  }
  __builtin_amdgcn_s_setprio(1);
#pragma unroll
  for (int nf = 0; nf < 4; nf++){
    union { u32 u[2]; bf16x4 v; } pa;
    pa.u[0] = pk[2*nf]; pa.u[1] = pk[2*nf+1];
#pragma unroll
    for (int fo = 0; fo < 4; fo++){
      const int d = fo * 16 + cl;
      const bf16x4 vf = *reinterpret_cast<const bf16x4*>(
          &VtC[d * 64 + (((nf * 4 + g) ^ (d & 7)) << 2)]);
      o[fo] = mfma16(pa.v, vf, o[fo]);
    }
  }
  __builtin_amdgcn_s_setprio(0);
}

// ---------------- causal flash attention: one KV sweep serves q-tiles {px, 31-px} ----------------
// TRIPLE-buffered staging, ONE barrier per tile (3-buffer hazard distance); vmcnt(4) keeps
// stage(t+1) in flight. 1D grid 1024, XCD swizzle: each XCD's 128 blocks share 8 bh's K/V.
__global__ __launch_bounds__(256) void k_flash(
    const u16* __restrict__ q, const u16* __restrict__ k,
    const u16* __restrict__ v, u16* __restrict__ ao)
{
  __shared__ u16 Ks[3][4096];   // [buf][kj*64 + swz-d], 16B-chunk swizzle: chunk' = chunk ^ (kj&7)
  __shared__ u16 Vt[3][4096];   // [buf][d*64 + swz-kj], 8B-chunk swizzle
  const int tid = threadIdx.x, wave = tid >> 6, lane = tid & 63;
  const int cl = lane & 15, g = lane >> 4;
  const int c0 = wave * 2;
  const int bid = blockIdx.x;
  const int swz = (bid & 7) * 128 + (bid >> 3);   // 1024/8 = 128 per XCD, bh-major
  const int bh = swz >> 4, px = swz & 15;
  const int qt1 = px, qt2 = NQT - 1 - px;
  const int ntot = qt2 + 1;
  const size_t base = (size_t)bh * NT * ND;
  const u16* kg0 = k + base;
  const u16* vg0 = v + base;

  // Q frags for both tiles: lane holds Q[q=cl][d=g*8+j]
  bf16x8 q1f0, q1f1, q2f0, q2f1;
  {
    const u16* qr1 = q + base + (size_t)(qt1 * 64 + wave * 16 + cl) * ND;
    q1f0 = *reinterpret_cast<const bf16x8*>(qr1 + g * 8);
    q1f1 = *reinterpret_cast<const bf16x8*>(qr1 + 32 + g * 8);
    const u16* qr2 = q + base + (size_t)(qt2 * 64 + wave * 16 + cl) * ND;
    q2f0 = *reinterpret_cast<const bf16x8*>(qr2 + g * 8);
    q2f1 = *reinterpret_cast<const bf16x8*>(qr2 + 32 + g * 8);
  }
  asm volatile("" : "+v"(q1f0), "+v"(q1f1), "+v"(q2f0), "+v"(q2f1));

  f32x4 o1[4] = {}, o2[4] = {};
  float m1 = -1e30f, l1 = 0.f, m2 = -1e30f, l2 = 0.f;

  // prologue: stage tile 0 -> buf 0 (4 gld_lds16 per wave)
  gld_lds16(&Ks[0][(c0    ) * 512], kg0 + (c0    ) * 512 + lane * 8);
  gld_lds16(&Ks[0][(c0 + 1) * 512], kg0 + (c0 + 1) * 512 + lane * 8);
  gld_lds16(&Vt[0][(c0    ) * 512], vg0 + (c0    ) * 512 + lane * 8);
  gld_lds16(&Vt[0][(c0 + 1) * 512], vg0 + (c0 + 1) * 512 + lane * 8);

  int cur = 0;
  for (int t = 0; t < ntot; ++t){
    const int nxt = (cur == 2) ? 0 : cur + 1;
    if (t + 1 < ntot){
      const u16* kg = kg0 + (size_t)(t + 1) * 4096;
      const u16* vg = vg0 + (size_t)(t + 1) * 4096;
      gld_lds16(&Ks[nxt][(c0    ) * 512], kg + (c0    ) * 512 + lane * 8);
      gld_lds16(&Ks[nxt][(c0 + 1) * 512], kg + (c0 + 1) * 512 + lane * 8);
      gld_lds16(&Vt[nxt][(c0    ) * 512], vg + (c0    ) * 512 + lane * 8);
      gld_lds16(&Vt[nxt][(c0 + 1) * 512], vg + (c0 + 1) * 512 + lane * 8);
      asm volatile("s_waitcnt vmcnt(4)" ::: "memory");   // own tile-t loads done; t+1 in flight
    } else {
      asm volatile("s_waitcnt vmcnt(0)" ::: "memory");
    }
    __builtin_amdgcn_sched_barrier(0);
    __builtin_amdgcn_s_barrier();    // the ONLY barrier per tile (3-buffer hazard distance)

    const u16* KsC = Ks[cur];
    const u16* VtC = Vt[cur];

    // state 2 (qt2): every tile
    {
      f32x4 s[4];
      qkt(KsC, q2f0, q2f1, cl, g, s);
      if (t == qt2) maskdiag(s, wave, cl, g);
      sm_pv(s, o2, m2, l2, VtC, cl, g);
    }
    // state 1 (qt1): tiles 0..qt1 (wave-uniform branch)
    if (t <= qt1){
      f32x4 s[4];
      qkt(KsC, q1f0, q1f1, cl, g, s);
      if (t == qt1) maskdiag(s, wave, cl, g);
      sm_pv(s, o1, m1, l1, VtC, cl, g);
    }
    cur = nxt;
  }

  // ---- epilogue: O/l for both q-tiles -> attn_out [B,T,C] bf16 ----
  float li1[4], li2[4];
#pragma unroll
  for (int r = 0; r < 4; r++){
    li1[r] = 1.0f / __shfl(l1, g * 4 + r);
    li2[r] = 1.0f / __shfl(l2, g * 4 + r);
  }
  const int b = bh >> 4, h = bh & 15;
#pragma unroll
  for (int fo = 0; fo < 4; fo++){
#pragma unroll
    for (int r = 0; r < 4; r++){
      const int c = h * 64 + fo * 16 + cl;
      const int t1 = qt1 * 64 + wave * 16 + g * 4 + r;
      ao[((size_t)b * NT + t1) * NC + c] = f2bf(o1[fo][r] * li1[r]);
      const int t2 = qt2 * 64 + wave * 16 + g * 4 + r;
      ao[((size_t)b * NT + t2) * NC + c] = f2bf(o2[fo][r] * li2[r]);
    }
  }
}

extern "C" void kernel_launch(void* const* d_in, const int* in_sizes, int n_in,
                              void* d_out, int out_size, void* d_ws, size_t ws_size,
                              hipStream_t stream){
  const float* x      = (const float*)d_in[0];
  const float* w_qkv  = (const float*)d_in[1];
  const float* b_qkv  = (const float*)d_in[2];
  const float* w_proj = (const float*)d_in[3];
  const float* b_proj = (const float*)d_in[4];
  float* out = (float*)d_out;

  u16* ws = (u16*)d_ws;
  u16* xb     = ws;                 //  [B,T,C] bf16
  u16* qb     = ws + 8388608;       //  [B,H,T,D] standard
  u16* kb     = ws + 16777216;      //  [B,H] x tiles, swizzled
  u16* vb     = ws + 25165824;      //  [B,H] x tiles, transposed+swizzled
  u16* aob    = ws + 33554432;      //  [B,T,C]
  u16* wqkvT  = ws + 41943040;      //  [3C,C]
  u16* wprojT = ws + 45088768;      //  [C,C]

  k_prep<<<12288, 256, 0, stream>>>(x, xb, w_qkv, wqkvT, w_proj, wprojT);
  k_gemm_qkv<<<1536, 256, 0, stream>>>(xb, wqkvT, b_qkv, qb, kb, vb);
  k_flash<<<1024, 256, 0, stream>>>(qb, kb, vb, aob);
  k_gemm_proj<<<512, 256, 0, stream>>>(aob, wprojT, b_proj, out);
}